// Round 6
// baseline (582.117 us; speedup 1.0000x reference)
//
#include <hip/hip_runtime.h>
#include <cstdint>
#include <cstddef>

#define N_ 32
#define C_ 256
#define H_ 56
#define W_ 56

typedef int v4i __attribute__((ext_vector_type(4)));
typedef uint32_t __attribute__((address_space(1))) glb_u32;
typedef uint32_t __attribute__((address_space(3))) lds_u32;

// ---- workspace layout ----
// sx: padded sign-activations, i8, [n][58 rows][68 w][256 c], chunk-swizzled:
//     16B-chunk ch of position (row,w) lives at slot (ch + w) & 15.
static constexpr size_t SX_BYTES = (size_t)N_ * 58 * 68 * 256;   // 32,309,248
static constexpr size_t WB_OFF   = SX_BYTES;
static constexpr size_t WB_BYTES = 36ull * 16 * 64 * 16;         // 589,824
static constexpr size_t SC_OFF   = WB_OFF + WB_BYTES;            // 256 floats

// sign BYTE of float bit-pattern u: 0x01 if >0, 0xff if <0, 0x00 if +-0.
// MUST be masked to 8 bits (round-4 bug: unmasked 0xffffffff smeared bytes).
__device__ __forceinline__ uint32_t sgnw(uint32_t u) {
    return (u & 0x7fffffffu) ? (((uint32_t)(((int)u) >> 31) | 1u) & 0xffu) : 0u;
}

// ---------------- pack_w body (runs as extra blocks of pack_x grid) ---------
__device__ void pack_w_body(const float* __restrict__ wt,
                            char* __restrict__ wB,
                            float* __restrict__ scaleg, int o) {
    __shared__ double red[256];
    int tid = threadIdx.x;
    const float* wo = wt + (size_t)o * 2304;

    double s = 0;
    for (int j = tid; j < 2304; j += 256) s += (double)wo[j];
    red[tid] = s;
    __syncthreads();
    for (int k = 128; k > 0; k >>= 1) {
        if (tid < k) red[tid] += red[tid + k];
        __syncthreads();
    }
    double mean = red[0] / 2304.0;
    __syncthreads();

    double s2 = 0;
    for (int j = tid; j < 2304; j += 256) s2 += fabs((double)wo[j] - mean);
    red[tid] = s2;
    __syncthreads();
    for (int k = 128; k > 0; k >>= 1) {
        if (tid < k) red[tid] += red[tid + k];
        __syncthreads();
    }
    if (tid == 0) scaleg[o] = (float)(red[0] / 2304.0);

    if (tid < 144) {
        int kiter = tid >> 2, q = tid & 3;     // kiter 0..35, q = k-quad
        int tap = kiter >> 2, cb = kiter & 3;
        int kh = tap / 3, kw = tap - kh * 3;
        int words[4];
        for (int g = 0; g < 4; ++g) {
            int word = 0;
            for (int b = 0; b < 4; ++b) {
                int c = cb * 64 + q * 16 + g * 4 + b;
                double v = (double)wo[c * 9 + kh * 3 + kw];
                int sg = (v > mean) - (v < mean);
                word |= (sg & 0xff) << (8 * b);
            }
            words[g] = word;
        }
        v4i pk = {words[0], words[1], words[2], words[3]};
        *(v4i*)(wB + (((size_t)kiter * 16 + (o >> 4)) * 64 + q * 16 + (o & 15)) * 16) = pk;
    }
}

// ---------------- kernel 1: pack x signs + halo + pack_w (fused grid) -------
// bx 0..48: 64-hw tile x 256 channels, in-register transpose. 49/50: halo zero.
// bx 51..58: pack_w for o = (bx-51)*32 + n.
__global__ __launch_bounds__(256) void pack_x(const float* __restrict__ x,
                                              char* __restrict__ sx,
                                              const float* __restrict__ wt,
                                              char* __restrict__ wB,
                                              float* __restrict__ scaleg) {
    int tid = threadIdx.x;
    int n   = blockIdx.y;
    v4i z = {0, 0, 0, 0};

    if (blockIdx.x >= 51) {
        pack_w_body(wt, wB, scaleg, (blockIdx.x - 51) * 32 + n);
        return;
    }
    if (blockIdx.x >= 49) {
        if (blockIdx.x == 49) {
            // rows 0 and 57, w 0..57
            for (int i = tid; i < 2 * 58 * 16; i += 256) {
                int r   = i / (58 * 16);
                int rem = i - r * (58 * 16);
                char* base = sx + ((size_t)n * 58 + (size_t)r * 57) * (68 * 256);
                *(v4i*)(base + (size_t)rem * 16) = z;
            }
        } else {
            // cols w=0,57 of rows 1..56 (zeros are swizzle-invariant)
            for (int i = tid; i < 56 * 32; i += 256) {
                int r = 1 + (i >> 5);
                int c = i & 31;
                int wpos = (c >> 4) * 57, ch = c & 15;
                *(v4i*)(sx + (((size_t)n * 58 + r) * 68 + wpos) * 256 + ch * 16) = z;
            }
        }
        return;
    }

    __shared__ char ob[64 * 256];       // 16 KB packed output tile (only LDS)
    int hw0 = blockIdx.x * 64;          // 49 tiles cover 3136 exactly

    int ch  = tid >> 4;                 // chunk index 0..15 = channels ch*16..+15
    int hw4 = tid & 15;                 // hw quad: hw = hw4*4 + h

    const float* xb = x + ((size_t)n * C_ + ch * 16) * 3136 + hw0 + hw4 * 4;

    uint32_t t[4][4];                   // t[p][h]: channels ch*16+4p..+3 at hw h
#pragma unroll
    for (int p = 0; p < 4; ++p) {
        uint32_t w0, w1, w2, w3;
        {
            float4 v = *(const float4*)(xb + (size_t)(4 * p + 0) * 3136);
            w0 = sgnw(__float_as_uint(v.x)) | (sgnw(__float_as_uint(v.y)) << 8) |
                 (sgnw(__float_as_uint(v.z)) << 16) | (sgnw(__float_as_uint(v.w)) << 24);
        }
        {
            float4 v = *(const float4*)(xb + (size_t)(4 * p + 1) * 3136);
            w1 = sgnw(__float_as_uint(v.x)) | (sgnw(__float_as_uint(v.y)) << 8) |
                 (sgnw(__float_as_uint(v.z)) << 16) | (sgnw(__float_as_uint(v.w)) << 24);
        }
        {
            float4 v = *(const float4*)(xb + (size_t)(4 * p + 2) * 3136);
            w2 = sgnw(__float_as_uint(v.x)) | (sgnw(__float_as_uint(v.y)) << 8) |
                 (sgnw(__float_as_uint(v.z)) << 16) | (sgnw(__float_as_uint(v.w)) << 24);
        }
        {
            float4 v = *(const float4*)(xb + (size_t)(4 * p + 3) * 3136);
            w3 = sgnw(__float_as_uint(v.x)) | (sgnw(__float_as_uint(v.y)) << 8) |
                 (sgnw(__float_as_uint(v.z)) << 16) | (sgnw(__float_as_uint(v.w)) << 24);
        }
        // 4x4 byte transpose: wg bytes are hw 0..3 of channel g; t[p][h] = byte h of each
        uint32_t lo01 = __builtin_amdgcn_perm(w1, w0, 0x05010400u); // w0.b0,w1.b0,w0.b1,w1.b1
        uint32_t hi01 = __builtin_amdgcn_perm(w1, w0, 0x07030602u); // w0.b2,w1.b2,w0.b3,w1.b3
        uint32_t lo23 = __builtin_amdgcn_perm(w3, w2, 0x05010400u);
        uint32_t hi23 = __builtin_amdgcn_perm(w3, w2, 0x07030602u);
        t[p][0] = __builtin_amdgcn_perm(lo23, lo01, 0x05040100u);
        t[p][1] = __builtin_amdgcn_perm(lo23, lo01, 0x07060302u);
        t[p][2] = __builtin_amdgcn_perm(hi23, hi01, 0x05040100u);
        t[p][3] = __builtin_amdgcn_perm(hi23, hi01, 0x07060302u);
    }

    // write 4 chunks (hw = hw4*4 + h) with rotation slot = (ch + hw) & 15
#pragma unroll
    for (int h = 0; h < 4; ++h) {
        int row  = hw4 * 4 + h;
        int slot = (ch + row) & 15;
        v4i c4 = {(int)t[0][h], (int)t[1][h], (int)t[2][h], (int)t[3][h]};
        *(v4i*)(ob + row * 256 + slot * 16) = c4;
    }
    __syncthreads();

    // copy-out: contiguous full 256B lines; apply GLOBAL swizzle slot=(ch+wpad)&15
#pragma unroll
    for (int j = 0; j < 4; ++j) {
        int i = tid + j * 256;                  // 0..1023 chunk index in tile
        int hwl3 = i >> 4, cc = i & 15;
        v4i v = *(const v4i*)(ob + hwl3 * 256 + ((cc + hwl3) & 15) * 16);
        int hw = hw0 + hwl3;
        int h = hw / 56, w = hw - h * 56;
        int slot = (cc + (w + 1)) & 15;         // pre-swizzle on padded w index
        *(v4i*)(sx + (((size_t)n * 58 + h + 1) * 68 + (w + 1)) * 256 + slot * 16) = v;
    }
}

// ---------------- kernel 2: persistent i8 MFMA implicit-GEMM conv -----------
// Grid (7, 32) = 224 blocks, 576 threads = 8 compute waves + 1 producer wave.
// Each block owns 8 output rows (2 tiles of 4). LDS = 10-row window:
// tile0 reads row-slots 0..5, tile1 reads 4..9. Producer wave stages tile0,
// barrier, then stages tile1's 4 new rows ON ITS OWN vmcnt FIFO while the 8
// compute waves run tile0's K-loop (counted B-ring waits no longer force-drain
// staging). Barrier, tile1 computes. Single dispatch round (224 <= 256 CUs).
__device__ __forceinline__ void stage_chunk(const char* src, char* xs, int i) {
    int pos = i >> 4;                        // row*58 + w, pos <= 347
    int row = (pos * 1130) >> 16;            // pos/58 (exact for pos<=347)
    int w   = pos - row * 58;
    const char* g = src + (((size_t)(row * 68 + w)) << 8) + ((size_t)(i & 15) << 4);
    char* l = xs + (size_t)i * 16;
    __builtin_amdgcn_global_load_lds((const glb_u32*)g, (lds_u32*)l, 16, 0, 0);
}

__device__ __forceinline__ void conv_tile(const char* __restrict__ xs,
                                          const v4i* __restrict__ wB,
                                          const float* __restrict__ scaleg,
                                          float* __restrict__ out,
                                          int wave, int lane, int n, int h0) {
    int lm = lane & 15, q = lane >> 4;
    int og = wave & 3, mg = wave >> 2;
    int kstart = __builtin_amdgcn_readfirstlane((9 * wave) >> 1);  // 0,4,9,13,18,22,27,31

    // per-m-frag geometry (lane-constant across k)
    int posb[7], slotb[7];
#pragma unroll
    for (int mf = 0; mf < 7; ++mf) {
        int m = mg * 112 + mf * 16 + lm;
        int r = m / 56;
        int wof = m - r * 56;
        posb[mf]  = r * 58 + wof;
        slotb[mf] = q + wof;
    }

    v4i acc[7][4];
#pragma unroll
    for (int mf = 0; mf < 7; ++mf)
#pragma unroll
        for (int of = 0; of < 4; ++of) { v4i z = {0, 0, 0, 0}; acc[mf][of] = z; }

    const v4i* wBw = wB + (size_t)(og * 4) * 64 + lane;   // + k*1024 + of*64

    auto wrap = [&](int t) { int k = kstart + t; return k >= 36 ? k - 36 : k; };
    auto loadB = [&](int k, v4i (&b)[4]) {
#pragma unroll
        for (int of = 0; of < 4; ++of) b[of] = wBw[(size_t)k * 1024 + of * 64];
    };

    v4i bR0[4], bR1[4], bR2[4];
    loadB(wrap(0), bR0);
    loadB(wrap(1), bR1);
    loadB(wrap(2), bR2);

    auto step = [&](v4i (&bReg)[4], int t) {
        int k = wrap(t);
        int tap = k >> 2, cb = k & 3;
        int dh = (tap * 11) >> 5;            // tap/3 for tap<=8
        int dw = tap - dh * 3;
        int pofs = dh * 58 + dw;
        int sofs = cb * 4 + dw;
        v4i a[7];
#pragma unroll
        for (int mf = 0; mf < 7; ++mf) {
            int pos  = posb[mf] + pofs;
            int slot = (slotb[mf] + sofs) & 15;
            a[mf] = *(const v4i*)(xs + ((size_t)pos << 8) + ((size_t)slot << 4));
        }
        __builtin_amdgcn_s_setprio(1);
#pragma unroll
        for (int mf = 0; mf < 7; ++mf)
#pragma unroll
            for (int of = 0; of < 4; ++of)
                acc[mf][of] = __builtin_amdgcn_mfma_i32_16x16x64_i8(
                    a[mf], bReg[of], acc[mf][of], 0, 0, 0);
        __builtin_amdgcn_s_setprio(0);
        // refill this ring slot for step t+3 (wrap keeps k in range; tail
        // refills re-load k=0..2 harmlessly)
        loadB(wrap(t + 3), bReg);
    };

    for (int t3 = 0; t3 < 12; ++t3) {
        int t = t3 * 3;
        step(bR0, t);
        step(bR1, t + 1);
        step(bR2, t + 2);
    }

    // epilogue: m = mg*112 + mf*16 + q*4 + reg; r = m/56 (float4-aligned), w = m%56
#pragma unroll
    for (int of = 0; of < 4; ++of) {
        int o = og * 64 + of * 16 + lm;
        float s = scaleg[o];
#pragma unroll
        for (int mf = 0; mf < 7; ++mf) {
            int m  = mg * 112 + mf * 16 + q * 4;
            int r  = m / 56;
            int wb = m - r * 56;
            float* ob = out + ((size_t)(n * C_ + o) * H_ + h0 + r) * W_ + wb;
            float4 v = {s * (float)acc[mf][of].x, s * (float)acc[mf][of].y,
                        s * (float)acc[mf][of].z, s * (float)acc[mf][of].w};
            *(float4*)ob = v;
        }
    }
}

__global__ __launch_bounds__(576, 1) void conv_mfma(const char* __restrict__ sx,
                                                    const v4i* __restrict__ wB,
                                                    const float* __restrict__ scaleg,
                                                    float* __restrict__ out) {
    __shared__ char xs[10 * 58 * 256];   // 148,480 B (10-row window)
    int tid = threadIdx.x;
    int wave = tid >> 6, lane = tid & 63;
    int j = blockIdx.x, n = blockIdx.y;
    int h0 = j * 8;                      // output rows h0..h0+7; padded rows h0..h0+9

    const char* src = sx + ((size_t)n * 58 + h0) * (68 * 256);

    if (wave == 8) {
        // producer: stage tile0's 6 rows (padded h0..h0+5) -> slots 0..5
        for (int i = lane; i < 6 * 58 * 16; i += 64) stage_chunk(src, xs, i);
    }
    __syncthreads();   // auto vmcnt(0) on producer drains stage0

    if (wave == 8) {
        // stage tile1's 4 new rows (padded h0+6..h0+9) -> slots 6..9, hidden
        // under tile0 compute (producer's private vmcnt FIFO)
        const char* s2 = src + (size_t)6 * 68 * 256;
        char* x2 = xs + (size_t)6 * 58 * 256;
        for (int i = lane; i < 4 * 58 * 16; i += 64) stage_chunk(s2, x2, i);
    } else {
        conv_tile(xs, wB, scaleg, out, wave, lane, n, h0);           // tile0
    }
    __syncthreads();   // producer's auto vmcnt(0) guarantees slots 6..9 ready

    if (wave < 8)
        conv_tile(xs + (size_t)4 * 58 * 256, wB, scaleg, out, wave, lane, n, h0 + 4);
}

extern "C" void kernel_launch(void* const* d_in, const int* in_sizes, int n_in,
                              void* d_out, int out_size, void* d_ws, size_t ws_size,
                              hipStream_t stream) {
    const float* x   = (const float*)d_in[0];
    const float* wgt = (const float*)d_in[1];
    float* out = (float*)d_out;
    char* ws = (char*)d_ws;

    char*  sx = ws;
    char*  wb = ws + WB_OFF;
    float* sg = (float*)(ws + SC_OFF);

    pack_x<<<dim3(59, N_), dim3(256), 0, stream>>>(x, sx, wgt, wb, sg);
    conv_mfma<<<dim3(7, N_), dim3(576), 0, stream>>>(sx, (const v4i*)wb, sg, out);
}

// Round 7
// 265.646 us; speedup vs baseline: 2.1913x; 2.1913x over previous
//
#include <hip/hip_runtime.h>
#include <cstdint>
#include <cstddef>

#define N_ 32
#define C_ 256
#define H_ 56
#define W_ 56

typedef int v4i __attribute__((ext_vector_type(4)));
typedef uint32_t __attribute__((address_space(1))) glb_u32;
typedef uint32_t __attribute__((address_space(3))) lds_u32;

// ---- workspace layout ----
// sx: padded sign-activations, i8, [n][58 rows][68 w][256 c], chunk-swizzled:
//     16B-chunk ch of position (row,w) lives at slot (ch + w) & 15.
static constexpr size_t SX_BYTES = (size_t)N_ * 58 * 68 * 256;   // 32,309,248
static constexpr size_t WB_OFF   = SX_BYTES;
static constexpr size_t WB_BYTES = 36ull * 16 * 64 * 16;         // 589,824
static constexpr size_t SC_OFF   = WB_OFF + WB_BYTES;            // 256 floats

// sign BYTE of float bit-pattern u: 0x01 if >0, 0xff if <0, 0x00 if +-0.
// MUST be masked to 8 bits (round-4 bug: unmasked 0xffffffff smeared bytes).
__device__ __forceinline__ uint32_t sgnw(uint32_t u) {
    return (u & 0x7fffffffu) ? (((uint32_t)(((int)u) >> 31) | 1u) & 0xffu) : 0u;
}

// ---------------- pack_w body (runs as extra blocks of pack_x grid) ---------
__device__ void pack_w_body(const float* __restrict__ wt,
                            char* __restrict__ wB,
                            float* __restrict__ scaleg, int o) {
    __shared__ double red[256];
    int tid = threadIdx.x;
    const float* wo = wt + (size_t)o * 2304;

    double s = 0;
    for (int j = tid; j < 2304; j += 256) s += (double)wo[j];
    red[tid] = s;
    __syncthreads();
    for (int k = 128; k > 0; k >>= 1) {
        if (tid < k) red[tid] += red[tid + k];
        __syncthreads();
    }
    double mean = red[0] / 2304.0;
    __syncthreads();

    double s2 = 0;
    for (int j = tid; j < 2304; j += 256) s2 += fabs((double)wo[j] - mean);
    red[tid] = s2;
    __syncthreads();
    for (int k = 128; k > 0; k >>= 1) {
        if (tid < k) red[tid] += red[tid + k];
        __syncthreads();
    }
    if (tid == 0) scaleg[o] = (float)(red[0] / 2304.0);

    if (tid < 144) {
        int kiter = tid >> 2, q = tid & 3;     // kiter 0..35, q = k-quad
        int tap = kiter >> 2, cb = kiter & 3;
        int kh = tap / 3, kw = tap - kh * 3;
        int words[4];
        for (int g = 0; g < 4; ++g) {
            int word = 0;
            for (int b = 0; b < 4; ++b) {
                int c = cb * 64 + q * 16 + g * 4 + b;
                double v = (double)wo[c * 9 + kh * 3 + kw];
                int sg = (v > mean) - (v < mean);
                word |= (sg & 0xff) << (8 * b);
            }
            words[g] = word;
        }
        v4i pk = {words[0], words[1], words[2], words[3]};
        *(v4i*)(wB + (((size_t)kiter * 16 + (o >> 4)) * 64 + q * 16 + (o & 15)) * 16) = pk;
    }
}

// ---------------- kernel 1: pack x signs + halo + pack_w (fused grid) -------
// bx 0..48: 64-hw tile x 256 channels, in-register transpose. 49/50: halo zero.
// bx 51..58: pack_w for o = (bx-51)*32 + n.
__global__ __launch_bounds__(256) void pack_x(const float* __restrict__ x,
                                              char* __restrict__ sx,
                                              const float* __restrict__ wt,
                                              char* __restrict__ wB,
                                              float* __restrict__ scaleg) {
    int tid = threadIdx.x;
    int n   = blockIdx.y;
    v4i z = {0, 0, 0, 0};

    if (blockIdx.x >= 51) {
        pack_w_body(wt, wB, scaleg, (blockIdx.x - 51) * 32 + n);
        return;
    }
    if (blockIdx.x >= 49) {
        if (blockIdx.x == 49) {
            // rows 0 and 57, w 0..57
            for (int i = tid; i < 2 * 58 * 16; i += 256) {
                int r   = i / (58 * 16);
                int rem = i - r * (58 * 16);
                char* base = sx + ((size_t)n * 58 + (size_t)r * 57) * (68 * 256);
                *(v4i*)(base + (size_t)rem * 16) = z;
            }
        } else {
            // cols w=0,57 of rows 1..56 (zeros are swizzle-invariant)
            for (int i = tid; i < 56 * 32; i += 256) {
                int r = 1 + (i >> 5);
                int c = i & 31;
                int wpos = (c >> 4) * 57, ch = c & 15;
                *(v4i*)(sx + (((size_t)n * 58 + r) * 68 + wpos) * 256 + ch * 16) = z;
            }
        }
        return;
    }

    __shared__ char ob[64 * 256];       // 16 KB packed output tile (only LDS)
    int hw0 = blockIdx.x * 64;          // 49 tiles cover 3136 exactly

    int ch  = tid >> 4;                 // chunk index 0..15 = channels ch*16..+15
    int hw4 = tid & 15;                 // hw quad: hw = hw4*4 + h

    const float* xb = x + ((size_t)n * C_ + ch * 16) * 3136 + hw0 + hw4 * 4;

    uint32_t t[4][4];                   // t[p][h]: channels ch*16+4p..+3 at hw h
#pragma unroll
    for (int p = 0; p < 4; ++p) {
        uint32_t w0, w1, w2, w3;
        {
            float4 v = *(const float4*)(xb + (size_t)(4 * p + 0) * 3136);
            w0 = sgnw(__float_as_uint(v.x)) | (sgnw(__float_as_uint(v.y)) << 8) |
                 (sgnw(__float_as_uint(v.z)) << 16) | (sgnw(__float_as_uint(v.w)) << 24);
        }
        {
            float4 v = *(const float4*)(xb + (size_t)(4 * p + 1) * 3136);
            w1 = sgnw(__float_as_uint(v.x)) | (sgnw(__float_as_uint(v.y)) << 8) |
                 (sgnw(__float_as_uint(v.z)) << 16) | (sgnw(__float_as_uint(v.w)) << 24);
        }
        {
            float4 v = *(const float4*)(xb + (size_t)(4 * p + 2) * 3136);
            w2 = sgnw(__float_as_uint(v.x)) | (sgnw(__float_as_uint(v.y)) << 8) |
                 (sgnw(__float_as_uint(v.z)) << 16) | (sgnw(__float_as_uint(v.w)) << 24);
        }
        {
            float4 v = *(const float4*)(xb + (size_t)(4 * p + 3) * 3136);
            w3 = sgnw(__float_as_uint(v.x)) | (sgnw(__float_as_uint(v.y)) << 8) |
                 (sgnw(__float_as_uint(v.z)) << 16) | (sgnw(__float_as_uint(v.w)) << 24);
        }
        // 4x4 byte transpose: wg bytes are hw 0..3 of channel g; t[p][h] = byte h of each
        uint32_t lo01 = __builtin_amdgcn_perm(w1, w0, 0x05010400u); // w0.b0,w1.b0,w0.b1,w1.b1
        uint32_t hi01 = __builtin_amdgcn_perm(w1, w0, 0x07030602u); // w0.b2,w1.b2,w0.b3,w1.b3
        uint32_t lo23 = __builtin_amdgcn_perm(w3, w2, 0x05010400u);
        uint32_t hi23 = __builtin_amdgcn_perm(w3, w2, 0x07030602u);
        t[p][0] = __builtin_amdgcn_perm(lo23, lo01, 0x05040100u);
        t[p][1] = __builtin_amdgcn_perm(lo23, lo01, 0x07060302u);
        t[p][2] = __builtin_amdgcn_perm(hi23, hi01, 0x05040100u);
        t[p][3] = __builtin_amdgcn_perm(hi23, hi01, 0x07060302u);
    }

    // write 4 chunks (hw = hw4*4 + h) with rotation slot = (ch + hw) & 15
#pragma unroll
    for (int h = 0; h < 4; ++h) {
        int row  = hw4 * 4 + h;
        int slot = (ch + row) & 15;
        v4i c4 = {(int)t[0][h], (int)t[1][h], (int)t[2][h], (int)t[3][h]};
        *(v4i*)(ob + row * 256 + slot * 16) = c4;
    }
    __syncthreads();

    // copy-out: contiguous full 256B lines; apply GLOBAL swizzle slot=(ch+wpad)&15
#pragma unroll
    for (int j = 0; j < 4; ++j) {
        int i = tid + j * 256;                  // 0..1023 chunk index in tile
        int hwl3 = i >> 4, cc = i & 15;
        v4i v = *(const v4i*)(ob + hwl3 * 256 + ((cc + hwl3) & 15) * 16);
        int hw = hw0 + hwl3;
        int h = hw / 56, w = hw - h * 56;
        int slot = (cc + (w + 1)) & 15;         // pre-swizzle on padded w index
        *(v4i*)(sx + (((size_t)n * 58 + h + 1) * 68 + (w + 1)) * 256 + slot * 16) = v;
    }
}

// ---------------- kernel 2: i8 MFMA implicit-GEMM conv, lockstep phases -----
// R5 grid: 448 blocks x 512 threads (8 waves: og = wave&3, mg = wave>>2),
// 4 output rows/block, 6-row LDS window. K-loop rewritten as the proven
// 8-phase-style lockstep schedule (T3+T4+T5): per k-iter all waves do
// {issue B(k+1) global + A(k+1) ds_read -> RAW s_barrier (no auto vmcnt(0)
// drain) -> setprio(1) -> 28 MFMA on (aA,bA) -> setprio(0) -> RAW s_barrier}.
// Loads are consumed one full phase (~1100 cyc) after issue, so the
// compiler's counted waits land satisfied. xs is read-only in the loop, so
// raw barriers are memory-safe; all 512 threads execute them uniformly.
__device__ __forceinline__ void stage_chunk(const char* src, char* xs, int i) {
    int pos = i >> 4;                        // row*58 + w, pos <= 347
    int row = (pos * 1130) >> 16;            // pos/58 (exact for pos<=347)
    int w   = pos - row * 58;
    const char* g = src + (((size_t)(row * 68 + w)) << 8) + ((size_t)(i & 15) << 4);
    char* l = xs + (size_t)i * 16;
    __builtin_amdgcn_global_load_lds((const glb_u32*)g, (lds_u32*)l, 16, 0, 0);
}

__global__ __launch_bounds__(512, 2) void conv_mfma(const char* __restrict__ sx,
                                                    const v4i* __restrict__ wB,
                                                    const float* __restrict__ scaleg,
                                                    float* __restrict__ out) {
    __shared__ char xs[6 * 58 * 256];   // 89,088 B -> 1 block/CU
    int tid = threadIdx.x;
    int wave = tid >> 6, lane = tid & 63;
    int hq = blockIdx.x, n = blockIdx.y;
    int h0 = hq * 4;

    // stage 6 padded rows (sx rows h0..h0+5) via async global->LDS, linear dest
    const char* src = sx + ((size_t)n * 58 + h0) * (68 * 256);
#pragma unroll
    for (int it = 0; it < 10; ++it) stage_chunk(src, xs, tid + it * 512);
    if (tid < 448) stage_chunk(src, xs, tid + 5120);   // 5568 = 10*512 + 448

    int lm = lane & 15, q = lane >> 4;
    int og = wave & 3, mg = wave >> 2;

    // per-m-frag geometry (lane-constant across k)
    int posb[7], slotb[7];
#pragma unroll
    for (int mf = 0; mf < 7; ++mf) {
        int m = mg * 112 + mf * 16 + lm;
        int r = m / 56;
        int wof = m - r * 56;
        posb[mf]  = r * 58 + wof;
        slotb[mf] = q + wof;
    }

    v4i acc[7][4];
#pragma unroll
    for (int mf = 0; mf < 7; ++mf)
#pragma unroll
        for (int of = 0; of < 4; ++of) { v4i z = {0, 0, 0, 0}; acc[mf][of] = z; }

    const v4i* wBw = wB + (size_t)(og * 4) * 64 + lane;   // + k*1024 + of*64

    auto loadB = [&](int k, v4i (&b)[4]) {
#pragma unroll
        for (int of = 0; of < 4; ++of) b[of] = wBw[(size_t)k * 1024 + of * 64];
    };
    auto loadA = [&](int k, v4i (&a)[7]) {
        int tap = k >> 2, cb = k & 3;
        int dh = (tap * 11) >> 5;            // tap/3 for tap<=8
        int dw = tap - dh * 3;
        int pofs = dh * 58 + dw;
        int sofs = cb * 4 + dw;
#pragma unroll
        for (int mf = 0; mf < 7; ++mf) {
            int pos  = posb[mf] + pofs;
            int slot = (slotb[mf] + sofs) & 15;
            a[mf] = *(const v4i*)(xs + ((size_t)pos << 8) + ((size_t)slot << 4));
        }
    };

    __syncthreads();   // real barrier: drains stage global_load_lds

    v4i aA[7], aB[7], bA[4], bB[4];
    loadB(0, bA);
    loadA(0, aA);

    for (int t2 = 0; t2 < 18; ++t2) {
        int ke = 2 * t2;
        int ko = ke + 1;
        int kn = (ke + 2 >= 36) ? 0 : ke + 2;   // tail reload of k=0 is dead
        // ---- even phase: issue (ko) loads, barrier, MFMA(ke), barrier ----
        loadB(ko, bB);
        loadA(ko, aB);
        __builtin_amdgcn_s_barrier();
        __builtin_amdgcn_s_setprio(1);
#pragma unroll
        for (int mf = 0; mf < 7; ++mf)
#pragma unroll
            for (int of = 0; of < 4; ++of)
                acc[mf][of] = __builtin_amdgcn_mfma_i32_16x16x64_i8(
                    aA[mf], bA[of], acc[mf][of], 0, 0, 0);
        __builtin_amdgcn_s_setprio(0);
        __builtin_amdgcn_s_barrier();
        // ---- odd phase: issue (kn) loads, barrier, MFMA(ko), barrier ----
        loadB(kn, bA);
        loadA(kn, aA);
        __builtin_amdgcn_s_barrier();
        __builtin_amdgcn_s_setprio(1);
#pragma unroll
        for (int mf = 0; mf < 7; ++mf)
#pragma unroll
            for (int of = 0; of < 4; ++of)
                acc[mf][of] = __builtin_amdgcn_mfma_i32_16x16x64_i8(
                    aB[mf], bB[of], acc[mf][of], 0, 0, 0);
        __builtin_amdgcn_s_setprio(0);
        __builtin_amdgcn_s_barrier();
    }

    // epilogue: m = mg*112 + mf*16 + q*4 + reg; r = m/56 (float4-aligned), w = m%56
#pragma unroll
    for (int of = 0; of < 4; ++of) {
        int o = og * 64 + of * 16 + lm;
        float s = scaleg[o];
#pragma unroll
        for (int mf = 0; mf < 7; ++mf) {
            int m  = mg * 112 + mf * 16 + q * 4;
            int r  = m / 56;
            int wb = m - r * 56;
            float* ob = out + ((size_t)(n * C_ + o) * H_ + h0 + r) * W_ + wb;
            float4 v = {s * (float)acc[mf][of].x, s * (float)acc[mf][of].y,
                        s * (float)acc[mf][of].z, s * (float)acc[mf][of].w};
            *(float4*)ob = v;
        }
    }
}

extern "C" void kernel_launch(void* const* d_in, const int* in_sizes, int n_in,
                              void* d_out, int out_size, void* d_ws, size_t ws_size,
                              hipStream_t stream) {
    const float* x   = (const float*)d_in[0];
    const float* wgt = (const float*)d_in[1];
    float* out = (float*)d_out;
    char* ws = (char*)d_ws;

    char*  sx = ws;
    char*  wb = ws + WB_OFF;
    float* sg = (float*)(ws + SC_OFF);

    pack_x<<<dim3(59, N_), dim3(256), 0, stream>>>(x, sx, wgt, wb, sg);
    conv_mfma<<<dim3(14, N_), dim3(512), 0, stream>>>(sx, (const v4i*)wb, sg, out);
}

// Round 8
// 246.893 us; speedup vs baseline: 2.3578x; 1.0760x over previous
//
#include <hip/hip_runtime.h>
#include <cstdint>
#include <cstddef>

#define N_ 32
#define C_ 256
#define H_ 56
#define W_ 56

typedef int v4i __attribute__((ext_vector_type(4)));

// ---- workspace layout ----
static constexpr size_t WB_BYTES = 36ull * 16 * 64 * 16;         // 589,824
static constexpr size_t SC_OFF   = WB_BYTES;                     // 256 floats

// sign BYTE of float bit-pattern u: 0x01 if >0, 0xff if <0, 0x00 if +-0.
// MUST be masked to 8 bits (round-4 bug: unmasked 0xffffffff smeared bytes).
__device__ __forceinline__ uint32_t sgnw(uint32_t u) {
    return (u & 0x7fffffffu) ? (((uint32_t)(((int)u) >> 31) | 1u) & 0xffu) : 0u;
}

// ---------------- kernel 1: binarize weights into MFMA B-fragment layout ----
__global__ __launch_bounds__(256) void pack_w(const float* __restrict__ wt,
                                              char* __restrict__ wB,
                                              float* __restrict__ scaleg) {
    __shared__ double red[256];
    int o = blockIdx.x, tid = threadIdx.x;
    const float* wo = wt + (size_t)o * 2304;

    double s = 0;
    for (int j = tid; j < 2304; j += 256) s += (double)wo[j];
    red[tid] = s;
    __syncthreads();
    for (int k = 128; k > 0; k >>= 1) {
        if (tid < k) red[tid] += red[tid + k];
        __syncthreads();
    }
    double mean = red[0] / 2304.0;
    __syncthreads();

    double s2 = 0;
    for (int j = tid; j < 2304; j += 256) s2 += fabs((double)wo[j] - mean);
    red[tid] = s2;
    __syncthreads();
    for (int k = 128; k > 0; k >>= 1) {
        if (tid < k) red[tid] += red[tid + k];
        __syncthreads();
    }
    if (tid == 0) scaleg[o] = (float)(red[0] / 2304.0);

    if (tid < 144) {
        int kiter = tid >> 2, q = tid & 3;     // kiter 0..35, q = k-quad
        int tap = kiter >> 2, cb = kiter & 3;
        int kh = tap / 3, kw = tap - kh * 3;
        int words[4];
        for (int g = 0; g < 4; ++g) {
            int word = 0;
            for (int b = 0; b < 4; ++b) {
                int c = cb * 64 + q * 16 + g * 4 + b;
                double v = (double)wo[c * 9 + kh * 3 + kw];
                int sg = (v > mean) - (v < mean);
                word |= (sg & 0xff) << (8 * b);
            }
            words[g] = word;
        }
        v4i pk = {words[0], words[1], words[2], words[3]};
        *(v4i*)(wB + (((size_t)kiter * 16 + (o >> 4)) * 64 + q * 16 + (o & 15)) * 16) = pk;
    }
}

// ---------------- kernel 2: FUSED pack + i8 MFMA implicit-GEMM conv ---------
// Grid (14, 32), 512 threads = 8 waves (og = wave&3, mg = wave>>2), 4 output
// rows/block. Stage phase reads x (fp32) directly: sign in-register, verified
// v_perm 4x4 byte-transpose, ds_write into the swizzled 6-row xs window
// (xs[pos = R*58 + wp][slot16B], slot = (chunk + wp) & 15). K-loop/epilogue =
// R5's proven engine: 3-deep counted B register ring + per-wave k-rotation
// + setprio around the 28-MFMA cluster.
__global__ __launch_bounds__(512, 2) void conv_mfma(const float* __restrict__ x,
                                                    const v4i* __restrict__ wB,
                                                    const float* __restrict__ scaleg,
                                                    float* __restrict__ out) {
    __shared__ char xs[6 * 58 * 256];   // 89,088 B -> 1 block/CU
    int tid = threadIdx.x;
    int wave = tid >> 6, lane = tid & 63;
    int hq = blockIdx.x, n = blockIdx.y;
    int h0 = hq * 4;

    // ---- stage: build 6 padded rows (input rows h0-1 .. h0+4) from x ----
    // zero halo columns wp = 0, 57 (6 rows x 2 wp x 16 chunks = 192 chunks)
    if (tid < 192) {
        int r  = tid >> 5;                 // 0..5
        int c2 = tid & 31;
        int wp = (c2 >> 4) * 57;           // 0 or 57
        int ch = c2 & 15;
        int slot = (ch + wp) & 15;
        v4i z = {0, 0, 0, 0};
        *(v4i*)(xs + ((size_t)(r * 58 + wp) << 8) + (slot << 4)) = z;
    }
    // interior units: (R 0..5, ch 0..15, wq 0..13); each = 16ch x 4w chunk set
    for (int u = tid; u < 6 * 16 * 14; u += 512) {
        int R   = u / 224;
        int rem = u - R * 224;
        int ch  = rem / 14;
        int wq  = rem - ch * 14;
        int ir  = h0 + R - 1;              // input row, clamp -> zeros
        if (ir < 0 || ir > 55) {
            v4i z = {0, 0, 0, 0};
#pragma unroll
            for (int h = 0; h < 4; ++h) {
                int wp = 1 + wq * 4 + h;
                int slot = (ch + wp) & 15;
                *(v4i*)(xs + ((size_t)(R * 58 + wp) << 8) + (slot << 4)) = z;
            }
            continue;
        }
        const float* xb = x + ((size_t)n * C_ + ch * 16) * 3136 + ir * 56 + wq * 4;
        uint32_t t[4][4];                  // t[p][h]: channels ch*16+4p..+3 at w-off h
#pragma unroll
        for (int p = 0; p < 4; ++p) {
            uint32_t w0, w1, w2, w3;
            {
                float4 v = *(const float4*)(xb + (size_t)(4 * p + 0) * 3136);
                w0 = sgnw(__float_as_uint(v.x)) | (sgnw(__float_as_uint(v.y)) << 8) |
                     (sgnw(__float_as_uint(v.z)) << 16) | (sgnw(__float_as_uint(v.w)) << 24);
            }
            {
                float4 v = *(const float4*)(xb + (size_t)(4 * p + 1) * 3136);
                w1 = sgnw(__float_as_uint(v.x)) | (sgnw(__float_as_uint(v.y)) << 8) |
                     (sgnw(__float_as_uint(v.z)) << 16) | (sgnw(__float_as_uint(v.w)) << 24);
            }
            {
                float4 v = *(const float4*)(xb + (size_t)(4 * p + 2) * 3136);
                w2 = sgnw(__float_as_uint(v.x)) | (sgnw(__float_as_uint(v.y)) << 8) |
                     (sgnw(__float_as_uint(v.z)) << 16) | (sgnw(__float_as_uint(v.w)) << 24);
            }
            {
                float4 v = *(const float4*)(xb + (size_t)(4 * p + 3) * 3136);
                w3 = sgnw(__float_as_uint(v.x)) | (sgnw(__float_as_uint(v.y)) << 8) |
                     (sgnw(__float_as_uint(v.z)) << 16) | (sgnw(__float_as_uint(v.w)) << 24);
            }
            // verified 4x4 byte transpose (R5): t[p][h] = byte h of w0..w3
            uint32_t lo01 = __builtin_amdgcn_perm(w1, w0, 0x05010400u);
            uint32_t hi01 = __builtin_amdgcn_perm(w1, w0, 0x07030602u);
            uint32_t lo23 = __builtin_amdgcn_perm(w3, w2, 0x05010400u);
            uint32_t hi23 = __builtin_amdgcn_perm(w3, w2, 0x07030602u);
            t[p][0] = __builtin_amdgcn_perm(lo23, lo01, 0x05040100u);
            t[p][1] = __builtin_amdgcn_perm(lo23, lo01, 0x07060302u);
            t[p][2] = __builtin_amdgcn_perm(hi23, hi01, 0x05040100u);
            t[p][3] = __builtin_amdgcn_perm(hi23, hi01, 0x07060302u);
        }
#pragma unroll
        for (int h = 0; h < 4; ++h) {
            int wp = 1 + wq * 4 + h;
            int slot = (ch + wp) & 15;
            v4i c4 = {(int)t[0][h], (int)t[1][h], (int)t[2][h], (int)t[3][h]};
            *(v4i*)(xs + ((size_t)(R * 58 + wp) << 8) + (slot << 4)) = c4;
        }
    }

    int lm = lane & 15, q = lane >> 4;
    int og = wave & 3, mg = wave >> 2;
    int kstart = __builtin_amdgcn_readfirstlane((9 * wave) >> 1);  // 0,4,9,13,18,22,27,31

    // per-m-frag geometry (lane-constant across k)
    int posb[7], slotb[7];
#pragma unroll
    for (int mf = 0; mf < 7; ++mf) {
        int m = mg * 112 + mf * 16 + lm;
        int r = m / 56;
        int wof = m - r * 56;
        posb[mf]  = r * 58 + wof;
        slotb[mf] = q + wof;
    }

    v4i acc[7][4];
#pragma unroll
    for (int mf = 0; mf < 7; ++mf)
#pragma unroll
        for (int of = 0; of < 4; ++of) { v4i z = {0, 0, 0, 0}; acc[mf][of] = z; }

    const v4i* wBw = wB + (size_t)(og * 4) * 64 + lane;   // + k*1024 + of*64

    auto wrap = [&](int t) { int k = kstart + t; return k >= 36 ? k - 36 : k; };
    auto loadB = [&](int k, v4i (&b)[4]) {
#pragma unroll
        for (int of = 0; of < 4; ++of) b[of] = wBw[(size_t)k * 1024 + of * 64];
    };

    __syncthreads();   // xs fully built

    v4i bR0[4], bR1[4], bR2[4];
    loadB(wrap(0), bR0);
    loadB(wrap(1), bR1);
    loadB(wrap(2), bR2);

    auto step = [&](v4i (&bReg)[4], int t) {
        int k = wrap(t);
        int tap = k >> 2, cb = k & 3;
        int dh = (tap * 11) >> 5;            // tap/3 for tap<=8
        int dw = tap - dh * 3;
        int pofs = dh * 58 + dw;
        int sofs = cb * 4 + dw;
        v4i a[7];
#pragma unroll
        for (int mf = 0; mf < 7; ++mf) {
            int pos  = posb[mf] + pofs;
            int slot = (slotb[mf] + sofs) & 15;
            a[mf] = *(const v4i*)(xs + ((size_t)pos << 8) + ((size_t)slot << 4));
        }
        __builtin_amdgcn_s_setprio(1);
#pragma unroll
        for (int mf = 0; mf < 7; ++mf)
#pragma unroll
            for (int of = 0; of < 4; ++of)
                acc[mf][of] = __builtin_amdgcn_mfma_i32_16x16x64_i8(
                    a[mf], bReg[of], acc[mf][of], 0, 0, 0);
        __builtin_amdgcn_s_setprio(0);
        // refill this ring slot for step t+3 (tail reloads k=0..2 harmlessly)
        loadB(wrap(t + 3), bReg);
    };

    for (int t3 = 0; t3 < 12; ++t3) {
        int t = t3 * 3;
        step(bR0, t);
        step(bR1, t + 1);
        step(bR2, t + 2);
    }

    // epilogue: m = mg*112 + mf*16 + q*4 + reg; r = m/56 (float4-aligned), w = m%56
#pragma unroll
    for (int of = 0; of < 4; ++of) {
        int o = og * 64 + of * 16 + lm;
        float s = scaleg[o];
#pragma unroll
        for (int mf = 0; mf < 7; ++mf) {
            int m  = mg * 112 + mf * 16 + q * 4;
            int r  = m / 56;
            int wb = m - r * 56;
            float* ob = out + ((size_t)(n * C_ + o) * H_ + h0 + r) * W_ + wb;
            float4 v = {s * (float)acc[mf][of].x, s * (float)acc[mf][of].y,
                        s * (float)acc[mf][of].z, s * (float)acc[mf][of].w};
            *(float4*)ob = v;
        }
    }
}

extern "C" void kernel_launch(void* const* d_in, const int* in_sizes, int n_in,
                              void* d_out, int out_size, void* d_ws, size_t ws_size,
                              hipStream_t stream) {
    const float* x   = (const float*)d_in[0];
    const float* wgt = (const float*)d_in[1];
    float* out = (float*)d_out;
    char* ws = (char*)d_ws;

    char*  wb = ws;
    float* sg = (float*)(ws + SC_OFF);

    pack_w<<<dim3(256), dim3(256), 0, stream>>>(wgt, wb, sg);
    conv_mfma<<<dim3(14, N_), dim3(512), 0, stream>>>(x, (const v4i*)wb, sg, out);
}